// Round 1
// baseline (417.905 us; speedup 1.0000x reference)
//
#include <hip/hip_runtime.h>

// Problem constants (fixed by setup_inputs / reference)
#define BB 8
#define CC 32
#define HH 512
#define WW 512
#define NN 64
#define RH 16      // HEIGHT
#define RW 128     // MAX_W

// res elements: B*N*C*RH*RW = 33,554,432 ; mask elements: B*N*RW = 65,536
#define RES_ELEMS ((size_t)BB * NN * CC * RH * RW)

// One thread per output element. Block = 256 threads = 2 j-rows x 128 k
// for a fixed (b,n,c). All box-dependent math derives from blockIdx only,
// so it is wave-uniform (divides execute once per wave).
__global__ __launch_bounds__(256) void roi_main(const float* __restrict__ img,
                                                const float* __restrict__ boxes,
                                                float* __restrict__ out) {
    const int tid = threadIdx.x;
    const int k   = tid & (RW - 1);      // 0..127
    const int jlo = tid >> 7;            // 0..1
    const unsigned blk = blockIdx.x;
    const int c = (blk >> 3) & (CC - 1);             // 8 blocks per (b,n,c)
    const int j = ((blk & 7) << 1) | jlo;            // 0..15
    const int n = (blk >> 8) & (NN - 1);
    const int b = blk >> 14;

    const float* bx = boxes + ((size_t)(b * NN + n) * 5);
    const float left   = bx[0];
    const float top    = bx[1];
    const float right  = bx[2];
    const float bottom = bx[3];

    const float bw = right - left;
    const float bh = bottom - top;
    const float aspect = (bh > 0.0f) ? (bw / fmaxf(bh, 1e-6f)) : 0.0f;
    int new_w = (int)(aspect * (float)RH);           // trunc toward zero, matches astype(int32)
    new_w = min(max(new_w, 0), RW);
    const float each_w = bw / (float)max(new_w - 1, 1);
    const float each_h = bh / (float)(RH - 1);

    float val = 0.0f;
    if (k < new_w) {
        const float xx = (float)k * each_w + left;
        const float yy = (float)j * each_h + top;

        int x0 = (int)floorf(xx);
        x0 = min(max(x0, 0), WW - 1);
        const int x1 = min(x0 + 1, WW - 1);
        int y0 = (int)floorf(yy);
        y0 = min(max(y0, 0), HH - 1);
        const int y1 = min(y0 + 1, HH - 1);

        const float* imf = img + ((size_t)(b * CC + c) * (HH * WW));
        const float Ia = imf[(size_t)y0 * WW + x0];
        const float Ib = imf[(size_t)y1 * WW + x0];
        const float Ic = imf[(size_t)y0 * WW + x1];
        const float Id = imf[(size_t)y1 * WW + x1];

        const float wx1 = (float)x1 - xx;
        const float wx0 = xx - (float)x0;
        const float wy1 = (float)y1 - yy;
        const float wy0 = yy - (float)y0;

        val = Ia * wx1 * wy1 + Ib * wx1 * wy0 + Ic * wx0 * wy1 + Id * wx0 * wy0;
    }

    out[(size_t)blk * 256 + tid] = val;
}

// mask[b][n][k] = (k < new_w) as float (read back as float32 by harness)
__global__ __launch_bounds__(256) void roi_mask(const float* __restrict__ boxes,
                                                float* __restrict__ mout) {
    const int t  = blockIdx.x * 256 + threadIdx.x;
    const int k  = t & (RW - 1);
    const int bn = t >> 7;                // b*NN + n
    const float* bx = boxes + (size_t)bn * 5;
    const float bw = bx[2] - bx[0];
    const float bh = bx[3] - bx[1];
    const float aspect = (bh > 0.0f) ? (bw / fmaxf(bh, 1e-6f)) : 0.0f;
    int new_w = (int)(aspect * (float)RH);
    new_w = min(max(new_w, 0), RW);
    mout[t] = (k < new_w) ? 1.0f : 0.0f;
}

extern "C" void kernel_launch(void* const* d_in, const int* in_sizes, int n_in,
                              void* d_out, int out_size, void* d_ws, size_t ws_size,
                              hipStream_t stream) {
    const float* img   = (const float*)d_in[0];
    const float* boxes = (const float*)d_in[1];
    float* out = (float*)d_out;

    const int main_blocks = (int)(RES_ELEMS / 256);          // 131072
    roi_main<<<main_blocks, 256, 0, stream>>>(img, boxes, out);

    const int mask_blocks = (BB * NN * RW) / 256;            // 256
    roi_mask<<<mask_blocks, 256, 0, stream>>>(boxes, out + RES_ELEMS);
}

// Round 2
// 379.443 us; speedup vs baseline: 1.1014x; 1.1014x over previous
//
#include <hip/hip_runtime.h>

// Problem constants (fixed by setup_inputs / reference)
#define BB 8
#define CC 32
#define HH 512
#define WW 512
#define NN 64
#define RH 16      // HEIGHT
#define RW 128     // MAX_W

#define RES_ELEMS ((size_t)BB * NN * CC * RH * RW)   // 33,554,432

// One block = one (b,n,c): 16x128 outputs. 256 threads: k = tid&127,
// jh = tid>>7; each thread computes 8 j-rows for its fixed k.
// x-dependent setup (xx/x0/x1/wx/addresses) is computed ONCE per thread and
// reused across all 8 j's. Adjacent-pixel loads (xg, xg+1) merge into
// global_load_dwordx2. Box math derives from blockIdx only -> wave-uniform
// (scalarized: divides execute once per wave).
__global__ __launch_bounds__(256) void roi_fused(const float* __restrict__ img,
                                                 const float* __restrict__ boxes,
                                                 float* __restrict__ out,
                                                 float* __restrict__ mout) {
    const int tid = threadIdx.x;
    const int k   = tid & (RW - 1);      // 0..127
    const int jh  = tid >> 7;            // 0..1 -> j = jh*8 + jj
    const unsigned blk = blockIdx.x;
    const int c   = blk & (CC - 1);
    const int bn  = blk >> 5;            // b*NN + n
    const int b   = bn >> 6;

    const float* bx = boxes + (size_t)bn * 5;
    const float left = bx[0];
    const float top  = bx[1];
    const float bw   = bx[2] - left;
    const float bh   = bx[3] - top;
    const float aspect = (bh > 0.0f) ? (bw / fmaxf(bh, 1e-6f)) : 0.0f;
    int new_w = (int)(aspect * (float)RH);          // trunc == astype(int32)
    new_w = min(max(new_w, 0), RW);
    const float each_w = bw / (float)max(new_w - 1, 1);
    const float each_h = bh / (float)(RH - 1);

    float* outp = out + (size_t)blk * (RH * RW) + (size_t)jh * (8 * RW) + k;

    // mask[b][n][k] (written once per (b,n), by the c==0 block's first half)
    if (c == 0 && jh == 0)
        mout[(size_t)bn * RW + k] = (k < new_w) ? 1.0f : 0.0f;

    if (k < new_w) {
        // x-setup: shared by all 8 j's of this thread
        const float xx = (float)k * each_w + left;
        int x0 = (int)floorf(xx);
        x0 = min(max(x0, 0), WW - 1);
        const int x1  = min(x0 + 1, WW - 1);
        const int xg  = min(x0, WW - 2);            // safe dwordx2 base
        const bool edge = (x0 == WW - 1);           // x1==x0 clamp case
        const float wx1 = (float)x1 - xx;
        const float wx0 = xx - (float)x0;

        const float* imf = img + ((size_t)(b * CC + c) * (HH * WW)) + xg;

        #pragma unroll
        for (int jj = 0; jj < 8; ++jj) {
            const int j = jh * 8 + jj;
            const float yy = (float)j * each_h + top;
            int y0 = (int)floorf(yy);
            y0 = min(max(y0, 0), HH - 1);
            const int y1 = min(y0 + 1, HH - 1);
            const float wy1 = (float)y1 - yy;
            const float wy0 = yy - (float)y0;

            const float* rowA = imf + (size_t)y0 * WW;
            const float* rowB = imf + (size_t)y1 * WW;
            const float a0 = rowA[0], a1 = rowA[1];  // merge -> dwordx2
            const float b0 = rowB[0], b1 = rowB[1];  // merge -> dwordx2
            const float Ia = edge ? a1 : a0;
            const float Ic = a1;
            const float Ib = edge ? b1 : b0;
            const float Id = b1;

            const float val = Ia * wx1 * wy1 + Ib * wx1 * wy0
                            + Ic * wx0 * wy1 + Id * wx0 * wy0;
            outp[(size_t)jj * RW] = val;
        }
    } else {
        #pragma unroll
        for (int jj = 0; jj < 8; ++jj)
            outp[(size_t)jj * RW] = 0.0f;
    }
}

extern "C" void kernel_launch(void* const* d_in, const int* in_sizes, int n_in,
                              void* d_out, int out_size, void* d_ws, size_t ws_size,
                              hipStream_t stream) {
    const float* img   = (const float*)d_in[0];
    const float* boxes = (const float*)d_in[1];
    float* out  = (float*)d_out;
    float* mout = out + RES_ELEMS;

    const int blocks = BB * NN * CC;                 // 16384
    roi_fused<<<blocks, 256, 0, stream>>>(img, boxes, out, mout);
}